// Round 1
// 9939.472 us; speedup vs baseline: 1.8056x; 1.8056x over previous
//
#include <hip/hip_runtime.h>
#include <stdint.h>

typedef __bf16 bf16;
typedef __bf16 bf16x8 __attribute__((ext_vector_type(8)));
typedef float f32x4 __attribute__((ext_vector_type(4)));
typedef unsigned int u32x4 __attribute__((ext_vector_type(4)));

#define T_STEPS 2048

// ws layout (bytes)
static constexpr size_t OFF_XBF  = 0;                 // x bf16: 128 MB (dead after gemm; 64 u32 flags reuse it)
static constexpr size_t OFF_WIHB = 134217728;         // w_ih bf16: 6 MB
static constexpr size_t OFF_WR   = 140509184;         // w_hh reordered bf16: 6 MB
static constexpr size_t OFF_GX   = 146800640;         // gx bf16 [t][g][48][32]: 384 MB
static constexpr size_t OFF_HBUF = 549453824;         // h broadcast, 2*32*1024 bf16
static constexpr size_t WS_NEED  = 549584960;

union PK8 { bf16 b[8]; uint4 u; };
union PK4 { bf16 b[4]; uint2 u; };

// ---------------- convert x to bf16 ----------------
__global__ void cvt_x_kernel(const float* __restrict__ x, bf16* __restrict__ xb) {
    size_t i = (size_t)blockIdx.x * 256 + threadIdx.x;   // 8 elements each, exact grid
    const float4* p = (const float4*)x + i * 2;
    float4 v0 = p[0], v1 = p[1];
    PK8 pk;
    pk.b[0]=(bf16)v0.x; pk.b[1]=(bf16)v0.y; pk.b[2]=(bf16)v0.z; pk.b[3]=(bf16)v0.w;
    pk.b[4]=(bf16)v1.x; pk.b[5]=(bf16)v1.y; pk.b[6]=(bf16)v1.z; pk.b[7]=(bf16)v1.w;
    ((uint4*)xb)[i] = pk.u;
}

// ---------------- convert w_ih, gather-reorder w_hh, convert h0 ----------------
__global__ void cvt_w_kernel(const float* __restrict__ wih, const float* __restrict__ whh,
                             const float* __restrict__ h0,
                             bf16* __restrict__ wihb, bf16* __restrict__ wr,
                             bf16* __restrict__ hbuf0) {
    int i = blockIdx.x * 256 + threadIdx.x;
    if (i < 786432) {                       // w_ih straight convert, 4 elems
        float4 v = ((const float4*)wih)[i];
        PK4 pk;
        pk.b[0]=(bf16)v.x; pk.b[1]=(bf16)v.y; pk.b[2]=(bf16)v.z; pk.b[3]=(bf16)v.w;
        ((uint2*)wihb)[i] = pk.u;
    } else if (i < 1572864) {               // w_hh -> wr[g][48][1024]; rows = {k16,f16,a16} of group g
        int d = (i - 786432) * 4;
        int g = d / 49152;
        int rem = d - g * 49152;
        int jr = rem >> 10, kk = rem & 1023;
        int srow = (jr >> 4) * 1024 + g * 16 + (jr & 15);
        float4 v = *(const float4*)(whh + (size_t)srow * 1024 + kk);
        PK4 pk;
        pk.b[0]=(bf16)v.x; pk.b[1]=(bf16)v.y; pk.b[2]=(bf16)v.z; pk.b[3]=(bf16)v.w;
        *(uint2*)(wr + d) = pk.u;
    } else {                                // h0 -> hbuf[0] bf16
        int j = (i - 1572864) * 4;
        float4 v = *(const float4*)(h0 + j);
        PK4 pk;
        pk.b[0]=(bf16)v.x; pk.b[1]=(bf16)v.y; pk.b[2]=(bf16)v.z; pk.b[3]=(bf16)v.w;
        *(uint2*)(hbuf0 + j) = pk.u;
    }
}

// ---------------- gx = x @ w_ih^T + (b_ih+b_hh), bf16 MFMA, 128x128x32 tiles ----------------
__global__ __launch_bounds__(256) void gemm_x_kernel(
        const bf16* __restrict__ A, const bf16* __restrict__ W,
        const float* __restrict__ bih, const float* __restrict__ bhh,
        bf16* __restrict__ gx) {
    __shared__ bf16 a_s[128 * 40];   // +8 pad
    __shared__ bf16 b_s[128 * 40];
    const int tid = threadIdx.x;
    const int wave = tid >> 6, lane = tid & 63;
    const int wm = wave & 1, wn = wave >> 1;
    const int col = lane & 15, row0 = (lane >> 4) << 2, kq = (lane >> 4) << 3;
    const int m0 = blockIdx.x * 128, n0 = blockIdx.y * 128;
    const int r0 = tid >> 2, c0 = (tid & 3) << 3;
    const int r1 = r0 + 64;
    f32x4 acc[4][4];
    #pragma unroll
    for (int mi = 0; mi < 4; ++mi)
        #pragma unroll
        for (int ni = 0; ni < 4; ++ni) {
            acc[mi][ni][0] = 0.f; acc[mi][ni][1] = 0.f;
            acc[mi][ni][2] = 0.f; acc[mi][ni][3] = 0.f;
        }
    for (int kt = 0; kt < 32; ++kt) {
        const int k0 = kt * 32;
        uint4 va0 = *(const uint4*)(A + (size_t)(m0 + r0) * 1024 + k0 + c0);
        uint4 vb0 = *(const uint4*)(W + (size_t)(n0 + r0) * 1024 + k0 + c0);
        uint4 va1 = *(const uint4*)(A + (size_t)(m0 + r1) * 1024 + k0 + c0);
        uint4 vb1 = *(const uint4*)(W + (size_t)(n0 + r1) * 1024 + k0 + c0);
        __syncthreads();
        *(uint4*)(a_s + r0 * 40 + c0) = va0;
        *(uint4*)(b_s + r0 * 40 + c0) = vb0;
        *(uint4*)(a_s + r1 * 40 + c0) = va1;
        *(uint4*)(b_s + r1 * 40 + c0) = vb1;
        __syncthreads();
        bf16x8 af[4], bfv[4];
        #pragma unroll
        for (int i = 0; i < 4; ++i)
            af[i] = *(const bf16x8*)(a_s + (wm * 64 + i * 16 + col) * 40 + kq);
        #pragma unroll
        for (int i = 0; i < 4; ++i)
            bfv[i] = *(const bf16x8*)(b_s + (wn * 64 + i * 16 + col) * 40 + kq);
        #pragma unroll
        for (int mi = 0; mi < 4; ++mi)
            #pragma unroll
            for (int ni = 0; ni < 4; ++ni)
                acc[mi][ni] = __builtin_amdgcn_mfma_f32_16x16x32_bf16(af[mi], bfv[ni], acc[mi][ni], 0, 0, 0);
    }
    #pragma unroll
    for (int mi = 0; mi < 4; ++mi) {
        const int mbase = m0 + wm * 64 + mi * 16;
        const int t = mbase >> 5;
        const int b0 = (mbase & 31) + row0;
        #pragma unroll
        for (int ni = 0; ni < 4; ++ni) {
            const int n = n0 + wn * 64 + ni * 16 + col;
            const int gt = n >> 10, ii = n & 1023;
            const float bias = bih[n] + bhh[n];
            const size_t off = (((size_t)t * 64 + (ii >> 4)) * 48 + gt * 16 + (ii & 15)) * 32 + b0;
            f32x4 v = acc[mi][ni];
            PK4 pk;
            pk.b[0]=(bf16)(v[0]+bias); pk.b[1]=(bf16)(v[1]+bias);
            pk.b[2]=(bf16)(v[2]+bias); pk.b[3]=(bf16)(v[3]+bias);
            *(uint2*)(gx + off) = pk.u;
        }
    }
}

// ---------------- persistent recurrent kernel ----------------
// 64 WGs x 384 thr. Weights (48x1024 per WG) live in VGPRs (128/lane).
// h exchange through LLC via sc0/sc1-coherent 16B loads/stores (no L2 flush,
// gx stays hot in L2). Barrier: per-WG flag array (no RMW), wave0-only poll.
__global__ __launch_bounds__(384, 1) void smru_rec_kernel(
        const bf16* __restrict__ wr, const bf16* __restrict__ gx,
        const float* __restrict__ h0,
        bf16* __restrict__ hbuf, float* __restrict__ out,
        unsigned int* __restrict__ flags) {
    extern __shared__ char smem[];
    bf16* h_s = (bf16*)smem;               // 2 x 32x512 bf16 = 65536 B (swizzled, no pad)
    float* g_s = (float*)(smem + 65536);   // 6 tiles x 16x17 fp32 = 6528 B
    const int g = blockIdx.x;
    const int tid = threadIdx.x;
    const int wave = tid >> 6, lane = tid & 63;
    const int mtile = wave & 1, ntile = wave >> 1;   // 6 waves: 2 m-tiles x 3 gate-tiles
    const int col = lane & 15, row0 = (lane >> 4) << 2, kq = (lane >> 4) << 3;
    const int f0 = g << 4;

    // ---- weights into registers: B-fragment rows (ntile*16+col), full K=1024 ----
    bf16x8 wreg[32];
    {
        const bf16* wrow = wr + (size_t)g * 49152 + (size_t)(ntile * 16 + col) * 1024 + kq;
        #pragma unroll
        for (int c2 = 0; c2 < 2; ++c2)
            #pragma unroll
            for (int kk = 0; kk < 16; ++kk)
                wreg[c2 * 16 + kk] = *(const bf16x8*)(wrow + c2 * 512 + kk * 32);
    }

    // fp32 recurrent state in registers
    const int b1 = tid >> 4, il1 = tid & 15;
    const int b2 = 24 + (tid >> 4);                  // valid when tid<128 (same il)
    float h1 = h0[b1 * 1024 + f0 + il1];
    float h2 = (tid < 128) ? h0[b2 * 1024 + f0 + il1] : 0.f;

    const int hrow = mtile * 16 + col;
    const int hswz = (hrow & 7) * 8;

    // preload gx for t=0
    uint2 gv = *(const uint2*)(gx + (((size_t)0 * 64 + g) * 48 + ntile * 16 + col) * 32
                               + mtile * 16 + row0);

    for (int t = 0; t < T_STEPS; ++t) {
        const bf16* hsrc = hbuf + (t & 1) * 32768;
        bf16* hdst = hbuf + ((t + 1) & 1) * 32768;

        // ---- stage chunk0 (cols 0..511): coherent 16B loads -> regs -> LDS buf0 ----
        u32x4 st0[6];
        #pragma unroll
        for (int j = 0; j < 6; ++j) {
            int s = tid + 384 * j;
            if (j < 5 || tid < 128) {
                int r = s >> 6, c8 = (s & 63) << 3;
                const bf16* p = hsrc + r * 1024 + c8;
                asm volatile("global_load_dwordx4 %0, %1, off sc0 sc1"
                             : "=v"(st0[j]) : "v"(p) : "memory");
            }
        }
        asm volatile("s_waitcnt vmcnt(0)" ::: "memory");
        __builtin_amdgcn_sched_barrier(0);
        #pragma unroll
        for (int j = 0; j < 6; ++j) {
            int s = tid + 384 * j;
            if (j < 5 || tid < 128) {
                int r = s >> 6, c8 = (s & 63) << 3;
                *(u32x4*)(h_s + r * 512 + (c8 ^ ((r & 7) * 8))) = st0[j];
            }
        }
        __syncthreads();

        // acc init from gx; second accumulator breaks the MFMA dep chain
        f32x4 acc, acc2;
        {
            union { uint2 u; bf16 b[4]; } pk; pk.u = gv;
            acc[0] = (float)pk.b[0]; acc[1] = (float)pk.b[1];
            acc[2] = (float)pk.b[2]; acc[3] = (float)pk.b[3];
            acc2[0] = 0.f; acc2[1] = 0.f; acc2[2] = 0.f; acc2[3] = 0.f;
        }

        // ---- load chunk1 (cols 512..1023) into registers (overlaps MFMA c0) ----
        u32x4 st1[6];
        #pragma unroll
        for (int j = 0; j < 6; ++j) {
            int s = tid + 384 * j;
            if (j < 5 || tid < 128) {
                int r = s >> 6, c8 = (s & 63) << 3;
                const bf16* p = hsrc + r * 1024 + 512 + c8;
                asm volatile("global_load_dwordx4 %0, %1, off sc0 sc1"
                             : "=v"(st1[j]) : "v"(p) : "memory");
            }
        }

        // ---- MFMA chunk0 (two independent 8-deep chains) ----
        const bf16* hb0 = h_s + hrow * 512;
        #pragma unroll
        for (int kk = 0; kk < 8; ++kk) {
            bf16x8 a0 = *(const bf16x8*)(hb0 + ((kk * 32 + kq) ^ hswz));
            bf16x8 a1 = *(const bf16x8*)(hb0 + (((kk + 8) * 32 + kq) ^ hswz));
            acc  = __builtin_amdgcn_mfma_f32_16x16x32_bf16(a0, wreg[kk], acc, 0, 0, 0);
            acc2 = __builtin_amdgcn_mfma_f32_16x16x32_bf16(a1, wreg[kk + 8], acc2, 0, 0, 0);
        }

        // ---- write chunk1 regs -> h_s buf1 ----
        asm volatile("s_waitcnt vmcnt(0)" ::: "memory");
        __builtin_amdgcn_sched_barrier(0);
        #pragma unroll
        for (int j = 0; j < 6; ++j) {
            int s = tid + 384 * j;
            if (j < 5 || tid < 128) {
                int r = s >> 6, c8 = (s & 63) << 3;
                *(u32x4*)(h_s + 16384 + r * 512 + (c8 ^ ((r & 7) * 8))) = st1[j];
            }
        }
        __syncthreads();

        // prefetch gx for t+1 (normal cached load; L2 stays valid)
        uint2 gvn;
        {
            int tn = (t + 1 < T_STEPS) ? t + 1 : t;
            gvn = *(const uint2*)(gx + (((size_t)tn * 64 + g) * 48 + ntile * 16 + col) * 32
                                  + mtile * 16 + row0);
        }

        // ---- MFMA chunk1 ----
        const bf16* hb1 = h_s + 16384 + hrow * 512;
        #pragma unroll
        for (int kk = 0; kk < 8; ++kk) {
            bf16x8 a0 = *(const bf16x8*)(hb1 + ((kk * 32 + kq) ^ hswz));
            bf16x8 a1 = *(const bf16x8*)(hb1 + (((kk + 8) * 32 + kq) ^ hswz));
            acc  = __builtin_amdgcn_mfma_f32_16x16x32_bf16(a0, wreg[16 + kk], acc, 0, 0, 0);
            acc2 = __builtin_amdgcn_mfma_f32_16x16x32_bf16(a1, wreg[24 + kk], acc2, 0, 0, 0);
        }

        // ---- gate exchange (stride-17 pad) ----
        float* gw = g_s + (ntile * 2 + mtile) * 272;
        gw[(row0 + 0) * 17 + col] = acc[0] + acc2[0];
        gw[(row0 + 1) * 17 + col] = acc[1] + acc2[1];
        gw[(row0 + 2) * 17 + col] = acc[2] + acc2[2];
        gw[(row0 + 3) * 17 + col] = acc[3] + acc2[3];
        __syncthreads();

        // ---- softmax + state update ----
        float hy1, hy2 = 0.f;
        {
            const int mt = b1 >> 4, rw = b1 & 15;
            const float gk = g_s[(0 + mt) * 272 + rw * 17 + il1];
            const float gf = g_s[(2 + mt) * 272 + rw * 17 + il1];
            const float ga = g_s[(4 + mt) * 272 + rw * 17 + il1];
            const float mx = fmaxf(gk, fmaxf(gf, ga));
            const float ek = __expf(gk - mx), ef = __expf(gf - mx), ea = __expf(ga - mx);
            const float inv = 1.0f / (ek + ef + ea);
            hy1 = ek * inv * h1 + ea * inv;
            h1 = hy1;
        }
        // paired coherent stores of next-h (even il stores 2xbf16 as u32)
        {
            union { bf16 h; unsigned short u; } cv; cv.h = (bf16)hy1;
            unsigned int nb = __shfl_down((unsigned int)cv.u, 1);
            if ((il1 & 1) == 0)
                __hip_atomic_store((unsigned int*)(hdst + b1 * 1024 + f0 + il1),
                                   (unsigned int)cv.u | (nb << 16),
                                   __ATOMIC_RELAXED, __HIP_MEMORY_SCOPE_AGENT);
        }
        if (tid < 128) {                                 // waves 0-1: second batch half
            const int mt = b2 >> 4, rw = b2 & 15;
            const float gk = g_s[(0 + mt) * 272 + rw * 17 + il1];
            const float gf = g_s[(2 + mt) * 272 + rw * 17 + il1];
            const float ga = g_s[(4 + mt) * 272 + rw * 17 + il1];
            const float mx = fmaxf(gk, fmaxf(gf, ga));
            const float ek = __expf(gk - mx), ef = __expf(gf - mx), ea = __expf(ga - mx);
            const float inv = 1.0f / (ek + ef + ea);
            hy2 = ek * inv * h2 + ea * inv;
            h2 = hy2;
            union { bf16 h; unsigned short u; } cv2; cv2.h = (bf16)hy2;
            unsigned int nb2 = __shfl_down((unsigned int)cv2.u, 1);
            if ((il1 & 1) == 0)
                __hip_atomic_store((unsigned int*)(hdst + b2 * 1024 + f0 + il1),
                                   (unsigned int)cv2.u | (nb2 << 16),
                                   __ATOMIC_RELAXED, __HIP_MEMORY_SCOPE_AGENT);
        }

        // ---- release: each wave drains its own stores, then WG sync, then flag ----
        asm volatile("s_waitcnt vmcnt(0)" ::: "memory");
        __syncthreads();
        if (tid == 0)
            __hip_atomic_store(flags + g, (unsigned int)(t + 1),
                               __ATOMIC_RELAXED, __HIP_MEMORY_SCOPE_AGENT);

        // out stores off the critical path (normal cached stores)
        out[((size_t)t * 32 + b1) * 1024 + f0 + il1] = hy1;
        if (tid < 128) out[((size_t)t * 32 + b2) * 1024 + f0 + il1] = hy2;

        gv = gvn;

        // ---- wait: wave0 polls all 64 flags in one wave-load; barrier releases ----
        if (t + 1 < T_STEPS) {
            const unsigned int tgt = (unsigned int)(t + 1);
            if (tid < 64) {
                for (;;) {
                    unsigned int f = __hip_atomic_load(flags + tid,
                        __ATOMIC_RELAXED, __HIP_MEMORY_SCOPE_AGENT);
                    if (__all((int)(f >= tgt))) break;
                }
            }
            __syncthreads();
            asm volatile("" ::: "memory");
        }
    }
}

extern "C" void kernel_launch(void* const* d_in, const int* in_sizes, int n_in,
                              void* d_out, int out_size, void* d_ws, size_t ws_size,
                              hipStream_t stream) {
    const float* x   = (const float*)d_in[0];
    const float* h0  = (const float*)d_in[1];
    const float* wih = (const float*)d_in[2];
    const float* whh = (const float*)d_in[3];
    const float* bih = (const float*)d_in[4];
    const float* bhh = (const float*)d_in[5];
    float* out = (float*)d_out;
    char* ws = (char*)d_ws;
    if (ws_size < WS_NEED) return;

    bf16* xb   = (bf16*)(ws + OFF_XBF);
    bf16* wihb = (bf16*)(ws + OFF_WIHB);
    bf16* wrp  = (bf16*)(ws + OFF_WR);
    bf16* gx   = (bf16*)(ws + OFF_GX);
    bf16* hbuf = (bf16*)(ws + OFF_HBUF);
    unsigned int* flags = (unsigned int*)(ws + OFF_XBF);   // xb dead after gemm

    cvt_x_kernel<<<32768, 256, 0, stream>>>(x, xb);
    cvt_w_kernel<<<6176, 256, 0, stream>>>(wih, whh, h0, wihb, wrp, hbuf);
    gemm_x_kernel<<<dim3(512, 24), 256, 0, stream>>>(xb, wihb, bih, bhh, gx);
    hipMemsetAsync(flags, 0, 256, stream);                 // zero barrier flags (after gemm reads xb)
    hipFuncSetAttribute((const void*)smru_rec_kernel,
                        hipFuncAttributeMaxDynamicSharedMemorySize, 72064);
    smru_rec_kernel<<<64, 384, 72064, stream>>>(wrp, gx, h0, hbuf, out, flags);
}